// Round 1
// baseline (1493.107 us; speedup 1.0000x reference)
//
#include <hip/hip_runtime.h>

#define N_NODES   100000
#define N_EDGES   1600000
#define NODE_DIM  64
#define EDGE_DIM  16
#define HIDDEN    64

__device__ __forceinline__ void load16(const float* __restrict__ p, float* v) {
    const float4* q = (const float4*)p;
    float4 a = q[0], b = q[1], c = q[2], d = q[3];
    v[0]=a.x;  v[1]=a.y;  v[2]=a.z;  v[3]=a.w;
    v[4]=b.x;  v[5]=b.y;  v[6]=b.z;  v[7]=b.w;
    v[8]=c.x;  v[9]=c.y;  v[10]=c.z; v[11]=c.w;
    v[12]=d.x; v[13]=d.y; v[14]=d.z; v[15]=d.w;
}

// One edge per lane. 256 threads = 4 waves = 256 edges per block.
// Grid = N_EDGES/256 (exact: 1.6M % 256 == 0).
__global__ __launch_bounds__(256) void edge_kernel(
    const float* __restrict__ x,
    const int*   __restrict__ ei,      // [2, E]: src rows then dst rows
    const float* __restrict__ ea,      // [E, 16]
    const float* __restrict__ W1,      // [144, 64]
    const float* __restrict__ b1,      // [64]
    const float* __restrict__ W2,      // [64, 64]
    const float* __restrict__ b2,      // [64]
    float* __restrict__ agg,           // [N, 64] zero-init
    float* __restrict__ cnt)           // [N] zero-init
{
    const int lane = threadIdx.x & 63;
    const int wave = threadIdx.x >> 6;
    const int e    = blockIdx.x * 256 + threadIdx.x;

    const int s = ei[e];
    const int d = ei[N_EDGES + e];

    // ---- layer 1: h = relu(v @ W1 + b1), v = [x[s], x[d], ea[e]] (144) ----
    float h[HIDDEN];
    #pragma unroll
    for (int j = 0; j < HIDDEN; j++) h[j] = b1[j];   // uniform -> s_load

    const float* xs  = x + (size_t)s * NODE_DIM;
    const float* xd  = x + (size_t)d * NODE_DIM;
    const float* eap = ea + (size_t)e * EDGE_DIM;

    #pragma unroll 1
    for (int c = 0; c < 9; c++) {                    // 9 chunks of 16 features
        const float* base = (c < 4) ? (xs + c * 16)
                          : (c < 8) ? (xd + (c - 4) * 16)
                          : eap;
        float v[16];
        load16(base, v);
        const float* w1r = W1 + c * 16 * HIDDEN;
        #pragma unroll
        for (int kk = 0; kk < 16; kk++) {
            #pragma unroll
            for (int j = 0; j < HIDDEN; j++)
                h[j] = fmaf(v[kk], w1r[kk * HIDDEN + j], h[j]);  // v_fmac v,s,v
        }
    }
    #pragma unroll
    for (int j = 0; j < HIDDEN; j++) h[j] = fmaxf(h[j], 0.0f);

    // ---- layer 2: msg = h @ W2 + b2, in halves of 32 cols; LDS transpose
    //      so atomics to agg[dst] are coalesced (lane = column). ----
    __shared__ float lds[4][64 * 33];
    float* my = lds[wave];
    const int l2    = lane & 31;
    const int ehalf = lane >> 5;

    #pragma unroll 1
    for (int half = 0; half < 2; half++) {
        float acc[32];
        #pragma unroll
        for (int j2 = 0; j2 < 32; j2++) acc[j2] = b2[half * 32 + j2];
        #pragma unroll
        for (int j = 0; j < HIDDEN; j++) {
            #pragma unroll
            for (int j2 = 0; j2 < 32; j2++)
                acc[j2] = fmaf(h[j], W2[j * HIDDEN + half * 32 + j2], acc[j2]);
        }
        // transpose via LDS: row = edge(lane), col = j2; stride 33 -> conflict-free
        #pragma unroll
        for (int j2 = 0; j2 < 32; j2++) my[lane * 33 + j2] = acc[j2];
        __syncthreads();
        // coalesced atomics: 2 edges per wave-instr (2 x 128B segments)
        #pragma unroll 1
        for (int eb = 0; eb < 64; eb += 2) {
            int   ee  = eb + ehalf;
            float val = my[ee * 33 + l2];
            int   dd  = __shfl(d, ee, 64);
            atomicAdd(&agg[(size_t)dd * HIDDEN + half * 32 + l2], val);
        }
        __syncthreads();
    }
    atomicAdd(&cnt[d], 1.0f);
}

// One node per wave, lane = output column. 4 nodes per 256-thread block.
__global__ __launch_bounds__(256) void node_kernel(
    const float* __restrict__ x,
    const float* __restrict__ agg,
    const float* __restrict__ cnt,
    const float* __restrict__ Wu,      // [128, 64]
    const float* __restrict__ bu,      // [64]
    float* __restrict__ out)
{
    const int lane = threadIdx.x & 63;
    int n = (blockIdx.x * 256 + threadIdx.x) >> 6;
    if (n >= N_NODES) return;                    // wave-uniform exit
    n = __builtin_amdgcn_readfirstlane(n);

    const float* xr = x   + (size_t)n * NODE_DIM;
    const float* ar = agg + (size_t)n * HIDDEN;
    const float  inv = 1.0f / (cnt[n] + 1e-6f);

    float a1 = bu[lane];
    float a2 = 0.0f;
    #pragma unroll
    for (int k = 0; k < NODE_DIM; k++)           // xr[k] uniform -> SGPR operand
        a1 = fmaf(xr[k], Wu[k * NODE_DIM + lane], a1);
    #pragma unroll
    for (int k = 0; k < HIDDEN; k++)
        a2 = fmaf(ar[k], Wu[(NODE_DIM + k) * NODE_DIM + lane], a2);

    const float u = a1 + inv * a2;
    out[(size_t)n * NODE_DIM + lane] = xr[lane] + fmaxf(u, 0.0f);
}

extern "C" void kernel_launch(void* const* d_in, const int* in_sizes, int n_in,
                              void* d_out, int out_size, void* d_ws, size_t ws_size,
                              hipStream_t stream) {
    const float* x  = (const float*)d_in[0];
    const int*   ei = (const int*)  d_in[1];
    const float* ea = (const float*)d_in[2];
    const float* W1 = (const float*)d_in[3];
    const float* b1 = (const float*)d_in[4];
    const float* W2 = (const float*)d_in[5];
    const float* b2 = (const float*)d_in[6];
    const float* Wu = (const float*)d_in[7];
    const float* bu = (const float*)d_in[8];
    float* out = (float*)d_out;

    float* agg = (float*)d_ws;                       // [N_NODES * 64]
    float* cnt = agg + (size_t)N_NODES * HIDDEN;     // [N_NODES]

    hipMemsetAsync(d_ws, 0,
                   (size_t)(N_NODES * HIDDEN + N_NODES) * sizeof(float), stream);

    edge_kernel<<<N_EDGES / 256, 256, 0, stream>>>(x, ei, ea, W1, b1, W2, b2, agg, cnt);
    node_kernel<<<(N_NODES + 3) / 4, 256, 0, stream>>>(x, agg, cnt, Wu, bu, out);
}

// Round 2
// 620.299 us; speedup vs baseline: 2.4071x; 2.4071x over previous
//
#include <hip/hip_runtime.h>

#define N_NODES  100000
#define N_EDGES  1600000
#define NODE_DIM 64
#define EDGE_DIM 16
#define HIDDEN   64

typedef __bf16 bf16x8 __attribute__((ext_vector_type(8)));
typedef unsigned short u16x8 __attribute__((ext_vector_type(8)));
typedef float f32x4 __attribute__((ext_vector_type(4)));

__device__ __forceinline__ unsigned short f2bf(float f) {
    unsigned int u = __float_as_uint(f);
    u += 0x7FFFu + ((u >> 16) & 1u);          // RNE
    return (unsigned short)(u >> 16);
}

__device__ __forceinline__ bf16x8 lds_frag(const unsigned short* p) {
    return __builtin_bit_cast(bf16x8, *(const u16x8*)p);
}

// convert 16 floats (4 float4s) -> 16 bf16, scaled, stored as 2x16B
__device__ __forceinline__ void cvt16(unsigned short* dst, const float4* src, float s) {
    float4 f0 = src[0], f1 = src[1], f2 = src[2], f3 = src[3];
    u16x8 p0, p1;
    p0[0]=f2bf(f0.x*s); p0[1]=f2bf(f0.y*s); p0[2]=f2bf(f0.z*s); p0[3]=f2bf(f0.w*s);
    p0[4]=f2bf(f1.x*s); p0[5]=f2bf(f1.y*s); p0[6]=f2bf(f1.z*s); p0[7]=f2bf(f1.w*s);
    p1[0]=f2bf(f2.x*s); p1[1]=f2bf(f2.y*s); p1[2]=f2bf(f2.z*s); p1[3]=f2bf(f2.w*s);
    p1[4]=f2bf(f3.x*s); p1[5]=f2bf(f3.y*s); p1[6]=f2bf(f3.z*s); p1[7]=f2bf(f3.w*s);
    *(u16x8*)dst       = p0;
    *(u16x8*)(dst + 8) = p1;
}

// ---- prep: transposed bf16 weights into workspace (re-run every launch) ----
__global__ void prep_kernel(const float* __restrict__ W1, const float* __restrict__ W2,
                            const float* __restrict__ Wu,
                            unsigned short* __restrict__ W1t,   // [64][160], k>=144 zero
                            unsigned short* __restrict__ W2t,   // [64][64]
                            unsigned short* __restrict__ Wut)   // [64][128]
{
    int t = blockIdx.x * 256 + threadIdx.x;
    int stride = gridDim.x * 256;
    for (int i = t; i < 64 * 160; i += stride) {
        int n = i / 160, k = i % 160;
        W1t[i] = (k < 144) ? f2bf(W1[k * 64 + n]) : (unsigned short)0;
    }
    for (int i = t; i < 64 * 64; i += stride) {
        int n = i / 64, k = i % 64;
        W2t[i] = f2bf(W2[k * 64 + n]);
    }
    for (int i = t; i < 64 * 128; i += stride) {
        int n = i / 128, k = i % 128;
        Wut[i] = f2bf(Wu[k * 64 + n]);
    }
}

// LDS strides (bf16 elems) chosen so stride*2 B mod 128 B keeps row-start banks
// spread: 168*2=336B=84dw (84%32=20, period 8 -> 2-way, free); 72*2=144B=36dw
// (36%32=4, period 8 -> 2-way); msg stride 66 f32 -> scatter reads conflict-free.
#define SA  168
#define SH  72
#define SW2 72
#define SM  66

// 64 edges / block, 4 waves. Wave w owns edge rows [16w,16w+16) end-to-end:
// GEMM1 -> relu -> GEMM2 need no inter-wave barrier (each wave reads/writes
// only its own row-tile of Ain/H/Msg); one barrier protects Ain-region reuse.
__global__ __launch_bounds__(256, 2) void edge_kernel(
    const float* __restrict__ x,
    const int*   __restrict__ ei,
    const float* __restrict__ ea,
    const unsigned short* __restrict__ W1t,
    const unsigned short* __restrict__ W2t,
    const float* __restrict__ b1,
    const float* __restrict__ b2,
    float* __restrict__ agg,
    float* __restrict__ cnt)
{
    __shared__ __align__(16) unsigned char  sAM[64 * SA * 2];   // Ain(bf16) then Msg(f32)
    __shared__ __align__(16) unsigned short sW1[64 * SA];
    __shared__ __align__(16) unsigned short sW2[64 * SW2];
    __shared__ __align__(16) unsigned short sH [64 * SH];
    __shared__ int sdst[64];

    unsigned short* sAin = (unsigned short*)sAM;
    float*          sMsg = (float*)sAM;

    const int t    = threadIdx.x;
    const int lane = t & 63;
    const int w    = t >> 6;
    const int e0   = blockIdx.x * 64;

    // ---- stage weights (global bf16, L2-hot) ----
    #pragma unroll
    for (int i = 0; i < 5; i++) {                 // 64*160/8 = 1280 chunks
        int c = t + i * 256;
        int n = c / 20, k8 = c % 20;
        *(u16x8*)&sW1[n * SA + k8 * 8] = *(const u16x8*)&W1t[c * 8];
    }
    #pragma unroll
    for (int i = 0; i < 2; i++) {                 // 64*64/8 = 512 chunks
        int c = t + i * 256;
        int n = c / 8, k8 = c % 8;
        *(u16x8*)&sW2[n * SW2 + k8 * 8] = *(const u16x8*)&W2t[c * 8];
    }

    // ---- gather 64 edges: [x[s] | x[d] | ea | 0] -> bf16 rows ----
    {
        const int el = t >> 2, q = t & 3;         // 4 threads per edge
        const int e  = e0 + el;
        const int s  = ei[e];
        const int d  = ei[N_EDGES + e];
        unsigned short* row = sAin + el * SA;
        cvt16(row + q * 16,      (const float4*)(x + (size_t)s * 64) + q * 4, 1.0f);
        cvt16(row + 64 + q * 16, (const float4*)(x + (size_t)d * 64) + q * 4, 1.0f);
        if (q == 0) {
            cvt16(row + 128, (const float4*)(ea + (size_t)e * 16), 1.0f);
        } else if (q == 1) {
            u16x8 z = {0,0,0,0,0,0,0,0};
            *(u16x8*)&row[144] = z;
            *(u16x8*)&row[152] = z;
        } else if (q == 2) {
            sdst[el] = d;
        } else {
            atomicAdd(&cnt[d], 1.0f);
        }
    }
    __syncthreads();

    const int col  = lane & 15;
    const int kq   = lane >> 4;           // 0..3
    const int arow = w * 16 + col;        // this lane's A row (edge)

    // ---- GEMM1: [64x160]x[160->64], wave w does rows 16w..16w+15, 4 col-tiles
    f32x4 acc[4] = {{0,0,0,0},{0,0,0,0},{0,0,0,0},{0,0,0,0}};
    #pragma unroll
    for (int ks = 0; ks < 5; ks++) {
        int ko = ks * 32 + kq * 8;
        bf16x8 a = lds_frag(&sAin[arow * SA + ko]);
        #pragma unroll
        for (int ct = 0; ct < 4; ct++) {
            bf16x8 b = lds_frag(&sW1[(ct * 16 + col) * SA + ko]);
            acc[ct] = __builtin_amdgcn_mfma_f32_16x16x32_bf16(a, b, acc[ct], 0, 0, 0);
        }
    }
    // bias + relu -> H (bf16), same-wave rows only
    #pragma unroll
    for (int ct = 0; ct < 4; ct++) {
        float bb = b1[ct * 16 + col];
        #pragma unroll
        for (int r = 0; r < 4; r++) {
            int row = w * 16 + kq * 4 + r;
            sH[row * SH + ct * 16 + col] = f2bf(fmaxf(acc[ct][r] + bb, 0.0f));
        }
    }

    // ---- GEMM2: [64x64]x[64x64] ----
    f32x4 m[4] = {{0,0,0,0},{0,0,0,0},{0,0,0,0},{0,0,0,0}};
    #pragma unroll
    for (int ks = 0; ks < 2; ks++) {
        int ko = ks * 32 + kq * 8;
        bf16x8 a = lds_frag(&sH[arow * SH + ko]);
        #pragma unroll
        for (int ct = 0; ct < 4; ct++) {
            bf16x8 b = lds_frag(&sW2[(ct * 16 + col) * SW2 + ko]);
            m[ct] = __builtin_amdgcn_mfma_f32_16x16x32_bf16(a, b, m[ct], 0, 0, 0);
        }
    }

    __syncthreads();   // all waves done reading Ain -> safe to overlay Msg

    #pragma unroll
    for (int ct = 0; ct < 4; ct++) {
        float bb = b2[ct * 16 + col];
        #pragma unroll
        for (int r = 0; r < 4; r++) {
            int row = w * 16 + kq * 4 + r;
            sMsg[row * SM + ct * 16 + col] = m[ct][r] + bb;
        }
    }

    // ---- scatter: one fully-coalesced 256B atomic per edge ----
    #pragma unroll 1
    for (int i = 0; i < 16; i++) {
        int el = w * 16 + i;
        int dd = sdst[el];
        float v = sMsg[el * SM + lane];
        atomicAdd(&agg[(size_t)dd * 64 + lane], v);
    }
}

// ---- node update: [64 nodes x 128] x [128 x 64] per block, coalesced rows ----
#define NSA 136
__global__ __launch_bounds__(256, 4) void node_kernel(
    const float* __restrict__ x,
    const float* __restrict__ agg,
    const float* __restrict__ cnt,
    const unsigned short* __restrict__ Wut,
    const float* __restrict__ bu,
    float* __restrict__ out)
{
    __shared__ __align__(16) unsigned short sA [64 * NSA];
    __shared__ __align__(16) unsigned short sWu[64 * NSA];
    const int t = threadIdx.x, lane = t & 63, w = t >> 6;
    const int n0 = blockIdx.x * 64;

    #pragma unroll
    for (int i = 0; i < 4; i++) {                 // 64*128/8 = 1024 chunks
        int c = t + i * 256;
        int n = c / 16, k8 = c % 16;
        *(u16x8*)&sWu[n * NSA + k8 * 8] = *(const u16x8*)&Wut[c * 8];
    }
    {
        const int nl = t >> 2, q = t & 3;
        const int n = n0 + nl;
        unsigned short* row = sA + nl * NSA;
        if (n < N_NODES) {
            cvt16(row + q * 16, (const float4*)(x + (size_t)n * 64) + q * 4, 1.0f);
            float inv = 1.0f / (cnt[n] + 1e-6f);
            cvt16(row + 64 + q * 16, (const float4*)(agg + (size_t)n * 64) + q * 4, inv);
        } else {
            u16x8 z = {0,0,0,0,0,0,0,0};
            *(u16x8*)&row[q * 16]      = z;
            *(u16x8*)&row[q * 16 + 8]  = z;
            *(u16x8*)&row[64 + q * 16]     = z;
            *(u16x8*)&row[64 + q * 16 + 8] = z;
        }
    }
    __syncthreads();

    const int col = lane & 15, kq = lane >> 4;
    const int arow = w * 16 + col;
    f32x4 acc[4] = {{0,0,0,0},{0,0,0,0},{0,0,0,0},{0,0,0,0}};
    #pragma unroll
    for (int ks = 0; ks < 4; ks++) {
        int ko = ks * 32 + kq * 8;
        bf16x8 a = lds_frag(&sA[arow * NSA + ko]);
        #pragma unroll
        for (int ct = 0; ct < 4; ct++) {
            bf16x8 b = lds_frag(&sWu[(ct * 16 + col) * NSA + ko]);
            acc[ct] = __builtin_amdgcn_mfma_f32_16x16x32_bf16(a, b, acc[ct], 0, 0, 0);
        }
    }
    #pragma unroll
    for (int ct = 0; ct < 4; ct++) {
        float bb = bu[ct * 16 + col];
        #pragma unroll
        for (int r = 0; r < 4; r++) {
            int row = w * 16 + kq * 4 + r;
            int n = n0 + row;
            if (n < N_NODES) {
                int c2 = ct * 16 + col;
                float xa = x[(size_t)n * 64 + c2];          // exact fp32 residual
                out[(size_t)n * 64 + c2] = xa + fmaxf(acc[ct][r] + bb, 0.0f);
            }
        }
    }
}

extern "C" void kernel_launch(void* const* d_in, const int* in_sizes, int n_in,
                              void* d_out, int out_size, void* d_ws, size_t ws_size,
                              hipStream_t stream) {
    const float* x  = (const float*)d_in[0];
    const int*   ei = (const int*)  d_in[1];
    const float* ea = (const float*)d_in[2];
    const float* W1 = (const float*)d_in[3];
    const float* b1 = (const float*)d_in[4];
    const float* W2 = (const float*)d_in[5];
    const float* b2 = (const float*)d_in[6];
    const float* Wu = (const float*)d_in[7];
    const float* bu = (const float*)d_in[8];
    float* out = (float*)d_out;

    float* agg = (float*)d_ws;                                  // [N,64]
    float* cnt = agg + (size_t)N_NODES * HIDDEN;                // [N]
    unsigned short* W1t = (unsigned short*)(cnt + N_NODES);     // [64][160] bf16
    unsigned short* W2t = W1t + 64 * 160;                       // [64][64]
    unsigned short* Wut = W2t + 64 * 64;                        // [64][128]

    hipMemsetAsync(d_ws, 0,
                   (size_t)(N_NODES * HIDDEN + N_NODES) * sizeof(float), stream);

    prep_kernel<<<88, 256, 0, stream>>>(W1, W2, Wu, W1t, W2t, Wut);
    edge_kernel<<<N_EDGES / 64, 256, 0, stream>>>(x, ei, ea, W1t, W2t, b1, b2, agg, cnt);
    node_kernel<<<(N_NODES + 63) / 64, 256, 0, stream>>>(x, agg, cnt, Wut, bu, out);
}

// Round 3
// 612.391 us; speedup vs baseline: 2.4382x; 1.0129x over previous
//
#include <hip/hip_runtime.h>

#define N_NODES  100000
#define N_EDGES  1600000
#define NODE_DIM 64
#define EDGE_DIM 16
#define HIDDEN   64
#define N_GROUPS 100000          // 16-edge groups
#define EDGE_BLOCKS 768          // 3 blocks/CU * 256 CUs

typedef __bf16 bf16x8 __attribute__((ext_vector_type(8)));
typedef unsigned short u16x8 __attribute__((ext_vector_type(8)));
typedef unsigned short u16x4 __attribute__((ext_vector_type(4)));
typedef float f32x4 __attribute__((ext_vector_type(4)));

__device__ __forceinline__ unsigned short f2bf(float f) {
    unsigned int u = __float_as_uint(f);
    u += 0x7FFFu + ((u >> 16) & 1u);          // RNE
    return (unsigned short)(u >> 16);
}

__device__ __forceinline__ bf16x8 lds_frag(const unsigned short* p) {
    return __builtin_bit_cast(bf16x8, *(const u16x8*)p);
}

__device__ __forceinline__ void cvt16v(unsigned short* dst,
                                       float4 f0, float4 f1, float4 f2, float4 f3) {
    u16x8 p0, p1;
    p0[0]=f2bf(f0.x); p0[1]=f2bf(f0.y); p0[2]=f2bf(f0.z); p0[3]=f2bf(f0.w);
    p0[4]=f2bf(f1.x); p0[5]=f2bf(f1.y); p0[6]=f2bf(f1.z); p0[7]=f2bf(f1.w);
    p1[0]=f2bf(f2.x); p1[1]=f2bf(f2.y); p1[2]=f2bf(f2.z); p1[3]=f2bf(f2.w);
    p1[4]=f2bf(f3.x); p1[5]=f2bf(f3.y); p1[6]=f2bf(f3.z); p1[7]=f2bf(f3.w);
    *(u16x8*)dst       = p0;
    *(u16x8*)(dst + 8) = p1;
}

__device__ __forceinline__ void cvt4v(unsigned short* dst, float4 f) {
    u16x4 p;
    p[0]=f2bf(f.x); p[1]=f2bf(f.y); p[2]=f2bf(f.z); p[3]=f2bf(f.w);
    *(u16x4*)dst = p;
}

// ---- prep: transposed bf16 weights into workspace (re-run every launch) ----
__global__ void prep_kernel(const float* __restrict__ W1, const float* __restrict__ W2,
                            const float* __restrict__ Wu,
                            unsigned short* __restrict__ W1t,   // [64][160], k>=144 zero
                            unsigned short* __restrict__ W2t,   // [64][64]
                            unsigned short* __restrict__ Wut)   // [64][128]
{
    int t = blockIdx.x * 256 + threadIdx.x;
    int stride = gridDim.x * 256;
    for (int i = t; i < 64 * 160; i += stride) {
        int n = i / 160, k = i % 160;
        W1t[i] = (k < 144) ? f2bf(W1[k * 64 + n]) : (unsigned short)0;
    }
    for (int i = t; i < 64 * 64; i += stride) {
        int n = i / 64, k = i % 64;
        W2t[i] = f2bf(W2[k * 64 + n]);
    }
    for (int i = t; i < 64 * 128; i += stride) {
        int n = i / 128, k = i % 128;
        Wut[i] = f2bf(Wu[k * 64 + n]);
    }
}

// LDS strides (elems): Ain 168 (row 336B = 84dw, 84%32=20 -> 2-way, free)
// W1 164 (82dw, 82%32=18 -> 16 distinct banks); H 72 (36dw -> 2-way);
// Msg overlays Ain, stride 84 dw (coalesced scatter reads, 2-way).
#define SA  168
#define SW1 164
#define SH  72
#define WAVE_LDS (16*SA*2 + 16*SH*2)   // 5376 + 2304 = 7680 B per wave

// Persistent: 768 blocks x 4 waves; wave-local 16-edge pipeline, no in-loop
// barriers (per-wave LDS regions; DS pipe is in-order per wave). Gather is
// software-pipelined one group ahead (regs hold x for g+1 across GEMM of g).
__global__ __launch_bounds__(256, 3) void edge_kernel(
    const float* __restrict__ x,
    const int*   __restrict__ ei,
    const float* __restrict__ ea,
    const unsigned short* __restrict__ W1t,
    const unsigned short* __restrict__ W2t,
    const float* __restrict__ b1,
    const float* __restrict__ b2,
    float* __restrict__ agg,
    float* __restrict__ cnt)
{
    __shared__ __align__(16) unsigned short sW1[64 * SW1];
    __shared__ __align__(16) unsigned char  sAH[4 * WAVE_LDS];
    __shared__ int sdst[64];

    const int t    = threadIdx.x;
    const int lane = t & 63;
    const int w    = t >> 6;

    // ---- stage W1 once per block ----
    #pragma unroll
    for (int i = 0; i < 5; i++) {
        int c = t + i * 256;             // 1280 chunks of 8
        int n = c / 20, k8 = c % 20;
        *(u16x8*)&sW1[n * SW1 + k8 * 8] = *(const u16x8*)&W1t[c * 8];
    }
    __syncthreads();                     // the only block-wide barrier

    unsigned short* myAin = (unsigned short*)(sAH + w * WAVE_LDS);
    float*          myMsg = (float*)myAin;                       // stride 84 dw
    unsigned short* myH   = (unsigned short*)(sAH + w * WAVE_LDS + 16 * SA * 2);

    // zero the K-pad (cols 144..160) once; gather never touches it
    if (lane < 16) {
        u16x8 z = {0,0,0,0,0,0,0,0};
        *(u16x8*)&myAin[lane * SA + 144] = z;
        *(u16x8*)&myAin[lane * SA + 152] = z;
    }

    const int col = lane & 15;
    const int kq  = lane >> 4;
    const int el  = lane >> 2;
    const int q   = lane & 3;

    // ---- per-lane constants in registers ----
    float b1r[4], b2r[4];
    u16x8 w2f[8];
    #pragma unroll
    for (int ct = 0; ct < 4; ct++) {
        b1r[ct] = b1[ct * 16 + col];
        b2r[ct] = b2[ct * 16 + col];
        #pragma unroll
        for (int ks = 0; ks < 2; ks++)
            w2f[ks * 4 + ct] = *(const u16x8*)&W2t[(ct * 16 + col) * 64 + ks * 32 + kq * 8];
    }

    const int TW = EDGE_BLOCKS * 4;
    const int gw = blockIdx.x * 4 + w;

    // ---- prologue: load group gw into registers ----
    int d_cur;
    float4 fx[8];
    float4 fe;
    {
        int e = gw * 16 + el;
        int s = ei[e];
        d_cur = ei[N_EDGES + e];
        const float4* ps = (const float4*)(x + (size_t)s * 64);
        const float4* pd = (const float4*)(x + (size_t)d_cur * 64);
        #pragma unroll
        for (int i = 0; i < 4; i++) { fx[i] = ps[q * 4 + i]; fx[4 + i] = pd[q * 4 + i]; }
        fe = ((const float4*)ea)[(size_t)gw * 64 + lane];
    }

    for (int g = gw; g < N_GROUPS; g += TW) {
        const int gn = g + TW;
        const bool more = gn < N_GROUPS;
        int sn = 0, dn = 0;
        if (more) {                       // prefetch next group's indices early
            int e2 = gn * 16 + el;
            sn = ei[e2];
            dn = ei[N_EDGES + e2];
        }

        // ---- commit group g to LDS (waits on loads issued last iter) ----
        unsigned short* row = myAin + el * SA;
        cvt16v(row + q * 16,      fx[0], fx[1], fx[2], fx[3]);
        cvt16v(row + 64 + q * 16, fx[4], fx[5], fx[6], fx[7]);
        cvt4v(&myAin[el * SA + 128 + q * 4], fe);   // ea: 1 float4/lane, coalesced
        if (q == 1) sdst[w * 16 + el] = d_cur;
        if (q == 2) atomicAdd(&cnt[d_cur], 1.0f);

        // ---- issue group g+1 gather into registers (hidden behind GEMM) ----
        if (more) {
            const float4* ps = (const float4*)(x + (size_t)sn * 64);
            const float4* pd = (const float4*)(x + (size_t)dn * 64);
            #pragma unroll
            for (int i = 0; i < 4; i++) { fx[i] = ps[q * 4 + i]; fx[4 + i] = pd[q * 4 + i]; }
            fe = ((const float4*)ea)[(size_t)gn * 64 + lane];
        }
        d_cur = dn;

        __builtin_amdgcn_wave_barrier();   // keep DS order: gather writes -> frag reads

        // ---- GEMM1: 16x160 @ 160x64 ----
        f32x4 acc[4] = {{0,0,0,0},{0,0,0,0},{0,0,0,0},{0,0,0,0}};
        #pragma unroll
        for (int ks = 0; ks < 5; ks++) {
            int ko = ks * 32 + kq * 8;
            bf16x8 a = lds_frag(&myAin[col * SA + ko]);
            #pragma unroll
            for (int ct = 0; ct < 4; ct++) {
                bf16x8 b = lds_frag(&sW1[(ct * 16 + col) * SW1 + ko]);
                acc[ct] = __builtin_amdgcn_mfma_f32_16x16x32_bf16(a, b, acc[ct], 0, 0, 0);
            }
        }
        // bias + relu -> H (wave-local)
        #pragma unroll
        for (int ct = 0; ct < 4; ct++) {
            #pragma unroll
            for (int r = 0; r < 4; r++)
                myH[(kq * 4 + r) * SH + ct * 16 + col] =
                    f2bf(fmaxf(acc[ct][r] + b1r[ct], 0.0f));
        }
        __builtin_amdgcn_wave_barrier();

        // ---- GEMM2: 16x64 @ 64x64 (B in registers) ----
        f32x4 m[4] = {{0,0,0,0},{0,0,0,0},{0,0,0,0},{0,0,0,0}};
        #pragma unroll
        for (int ks = 0; ks < 2; ks++) {
            int ko = ks * 32 + kq * 8;
            bf16x8 a = lds_frag(&myH[col * SH + ko]);
            #pragma unroll
            for (int ct = 0; ct < 4; ct++)
                m[ct] = __builtin_amdgcn_mfma_f32_16x16x32_bf16(
                    a, __builtin_bit_cast(bf16x8, w2f[ks * 4 + ct]), m[ct], 0, 0, 0);
        }
        // Msg (f32) overlays Ain region, stride 84 dw
        #pragma unroll
        for (int ct = 0; ct < 4; ct++) {
            #pragma unroll
            for (int r = 0; r < 4; r++)
                myMsg[(kq * 4 + r) * 84 + ct * 16 + col] = m[ct][r] + b2r[ct];
        }
        __builtin_amdgcn_wave_barrier();

        // ---- scatter: one coalesced 256B atomic per edge, fire-and-forget ----
        #pragma unroll 1
        for (int i = 0; i < 16; i++) {
            int   dd = sdst[w * 16 + i];
            float v  = myMsg[i * 84 + lane];
            atomicAdd(&agg[(size_t)dd * 64 + lane], v);
        }
        __builtin_amdgcn_wave_barrier();   // scatter reads before next gather writes
    }
}

// ---- node update: [64 nodes x 128] x [128 x 64] per block, coalesced rows ----
#define NSA 136
__global__ __launch_bounds__(256, 4) void node_kernel(
    const float* __restrict__ x,
    const float* __restrict__ agg,
    const float* __restrict__ cnt,
    const unsigned short* __restrict__ Wut,
    const float* __restrict__ bu,
    float* __restrict__ out)
{
    __shared__ __align__(16) unsigned short sA [64 * NSA];
    __shared__ __align__(16) unsigned short sWu[64 * NSA];
    const int t = threadIdx.x, lane = t & 63, w = t >> 6;
    const int n0 = blockIdx.x * 64;

    #pragma unroll
    for (int i = 0; i < 4; i++) {
        int c = t + i * 256;
        int n = c / 16, k8 = c % 16;
        *(u16x8*)&sWu[n * NSA + k8 * 8] = *(const u16x8*)&Wut[c * 8];
    }
    {
        const int nl = t >> 2, q = t & 3;
        const int n = n0 + nl;
        unsigned short* row = sA + nl * NSA;
        if (n < N_NODES) {
            const float4* px = (const float4*)(x + (size_t)n * 64);
            cvt16v(row + q * 16, px[q*4], px[q*4+1], px[q*4+2], px[q*4+3]);
            float inv = 1.0f / (cnt[n] + 1e-6f);
            const float4* pa = (const float4*)(agg + (size_t)n * 64);
            float4 a0 = pa[q*4], a1 = pa[q*4+1], a2 = pa[q*4+2], a3 = pa[q*4+3];
            a0.x*=inv; a0.y*=inv; a0.z*=inv; a0.w*=inv;
            a1.x*=inv; a1.y*=inv; a1.z*=inv; a1.w*=inv;
            a2.x*=inv; a2.y*=inv; a2.z*=inv; a2.w*=inv;
            a3.x*=inv; a3.y*=inv; a3.z*=inv; a3.w*=inv;
            cvt16v(row + 64 + q * 16, a0, a1, a2, a3);
        } else {
            u16x8 z = {0,0,0,0,0,0,0,0};
            *(u16x8*)&row[q * 16]          = z;
            *(u16x8*)&row[q * 16 + 8]      = z;
            *(u16x8*)&row[64 + q * 16]     = z;
            *(u16x8*)&row[64 + q * 16 + 8] = z;
        }
    }
    __syncthreads();

    const int col = lane & 15, kq = lane >> 4;
    const int arow = w * 16 + col;
    f32x4 acc[4] = {{0,0,0,0},{0,0,0,0},{0,0,0,0},{0,0,0,0}};
    #pragma unroll
    for (int ks = 0; ks < 4; ks++) {
        int ko = ks * 32 + kq * 8;
        bf16x8 a = lds_frag(&sA[arow * NSA + ko]);
        #pragma unroll
        for (int ct = 0; ct < 4; ct++) {
            bf16x8 b = lds_frag(&sWu[(ct * 16 + col) * NSA + ko]);
            acc[ct] = __builtin_amdgcn_mfma_f32_16x16x32_bf16(a, b, acc[ct], 0, 0, 0);
        }
    }
    #pragma unroll
    for (int ct = 0; ct < 4; ct++) {
        float bb = bu[ct * 16 + col];
        #pragma unroll
        for (int r = 0; r < 4; r++) {
            int row = w * 16 + kq * 4 + r;
            int n = n0 + row;
            if (n < N_NODES) {
                int c2 = ct * 16 + col;
                float xa = x[(size_t)n * 64 + c2];          // exact fp32 residual
                out[(size_t)n * 64 + c2] = xa + fmaxf(acc[ct][r] + bb, 0.0f);
            }
        }
    }
}

extern "C" void kernel_launch(void* const* d_in, const int* in_sizes, int n_in,
                              void* d_out, int out_size, void* d_ws, size_t ws_size,
                              hipStream_t stream) {
    const float* x  = (const float*)d_in[0];
    const int*   ei = (const int*)  d_in[1];
    const float* ea = (const float*)d_in[2];
    const float* W1 = (const float*)d_in[3];
    const float* b1 = (const float*)d_in[4];
    const float* W2 = (const float*)d_in[5];
    const float* b2 = (const float*)d_in[6];
    const float* Wu = (const float*)d_in[7];
    const float* bu = (const float*)d_in[8];
    float* out = (float*)d_out;

    float* agg = (float*)d_ws;                                  // [N,64]
    float* cnt = agg + (size_t)N_NODES * HIDDEN;                // [N]
    unsigned short* W1t = (unsigned short*)(cnt + N_NODES);     // [64][160] bf16
    unsigned short* W2t = W1t + 64 * 160;                       // [64][64]
    unsigned short* Wut = W2t + 64 * 64;                        // [64][128]

    hipMemsetAsync(d_ws, 0,
                   (size_t)(N_NODES * HIDDEN + N_NODES) * sizeof(float), stream);

    prep_kernel<<<88, 256, 0, stream>>>(W1, W2, Wu, W1t, W2t, Wut);
    edge_kernel<<<EDGE_BLOCKS, 256, 0, stream>>>(x, ei, ea, W1t, W2t, b1, b2, agg, cnt);
    node_kernel<<<(N_NODES + 63) / 64, 256, 0, stream>>>(x, agg, cnt, Wut, bu, out);
}

// Round 5
// 470.626 us; speedup vs baseline: 3.1726x; 1.3012x over previous
//
#include <hip/hip_runtime.h>

#define N_NODES  100000
#define N_EDGES  1600000
#define NODE_DIM 64
#define EDGE_DIM 16
#define HIDDEN   64
#define N_GROUPS 100000          // 16-edge groups
#define EDGE_BLOCKS 768          // 3 blocks/CU * 256 CUs

typedef __bf16 bf16x8 __attribute__((ext_vector_type(8)));
typedef unsigned short u16x8 __attribute__((ext_vector_type(8)));
typedef unsigned short u16x4 __attribute__((ext_vector_type(4)));
typedef float f32x4 __attribute__((ext_vector_type(4)));
typedef float f32x2 __attribute__((ext_vector_type(2)));

__device__ __forceinline__ unsigned short f2bf(float f) {
    unsigned int u = __float_as_uint(f);
    u += 0x7FFFu + ((u >> 16) & 1u);          // RNE
    return (unsigned short)(u >> 16);
}

__device__ __forceinline__ float bf2f(unsigned short s) {
    return __uint_as_float((unsigned int)s << 16);
}

__device__ __forceinline__ bf16x8 lds_frag(const unsigned short* p) {
    return __builtin_bit_cast(bf16x8, *(const u16x8*)p);
}

__device__ __forceinline__ void cvt16v(unsigned short* dst,
                                       float4 f0, float4 f1, float4 f2, float4 f3) {
    u16x8 p0, p1;
    p0[0]=f2bf(f0.x); p0[1]=f2bf(f0.y); p0[2]=f2bf(f0.z); p0[3]=f2bf(f0.w);
    p0[4]=f2bf(f1.x); p0[5]=f2bf(f1.y); p0[6]=f2bf(f1.z); p0[7]=f2bf(f1.w);
    p1[0]=f2bf(f2.x); p1[1]=f2bf(f2.y); p1[2]=f2bf(f2.z); p1[3]=f2bf(f2.w);
    p1[4]=f2bf(f3.x); p1[5]=f2bf(f3.y); p1[6]=f2bf(f3.z); p1[7]=f2bf(f3.w);
    *(u16x8*)dst       = p0;
    *(u16x8*)(dst + 8) = p1;
}

__device__ __forceinline__ void cvt4v(unsigned short* dst, float4 f) {
    u16x4 p;
    p[0]=f2bf(f.x); p[1]=f2bf(f.y); p[2]=f2bf(f.z); p[3]=f2bf(f.w);
    *(u16x4*)dst = p;
}

// packed 2xbf16 atomic add: one 4B RMW op covers two columns
__device__ __forceinline__ void atomic_pk_add_bf16(unsigned short* p, unsigned int v) {
    asm volatile("global_atomic_pk_add_bf16 %0, %1, off"
                 :: "v"(p), "v"(v) : "memory");
}

// ---- prep: bf16 weights (transposed) + bf16 copy of x ----
__global__ void prep_kernel(const float* __restrict__ W1, const float* __restrict__ W2,
                            const float* __restrict__ Wu, const float* __restrict__ x,
                            unsigned short* __restrict__ W1t,   // [64][160], k>=144 zero
                            unsigned short* __restrict__ W2t,   // [64][64]
                            unsigned short* __restrict__ Wut,   // [64][128]
                            unsigned short* __restrict__ xb)    // [N][64] bf16
{
    int t = blockIdx.x * 256 + threadIdx.x;
    int stride = gridDim.x * 256;
    for (int i = t; i < N_NODES * 64 / 4; i += stride) {
        float4 f = ((const float4*)x)[i];
        cvt4v(&xb[i * 4], f);
    }
    for (int i = t; i < 64 * 160; i += stride) {
        int n = i / 160, k = i % 160;
        W1t[i] = (k < 144) ? f2bf(W1[k * 64 + n]) : (unsigned short)0;
    }
    for (int i = t; i < 64 * 64; i += stride) {
        int n = i / 64, k = i % 64;
        W2t[i] = f2bf(W2[k * 64 + n]);
    }
    for (int i = t; i < 64 * 128; i += stride) {
        int n = i / 128, k = i % 128;
        Wut[i] = f2bf(Wu[k * 64 + n]);
    }
}

// LDS strides (elems): Ain 168 (row 336B = 84dw, 84%32=20 -> 2-way, free)
// W1 164; H 72; Msg overlays Ain, stride 84 dw.
#define SA  168
#define SW1 164
#define SH  72
#define WAVE_LDS (16*SA*2 + 16*SH*2)   // 7680 B per wave

__global__ __launch_bounds__(256, 3) void edge_kernel(
    const unsigned short* __restrict__ xb,
    const int*   __restrict__ ei,
    const float* __restrict__ ea,
    const unsigned short* __restrict__ W1t,
    const unsigned short* __restrict__ W2t,
    const float* __restrict__ b1,
    const float* __restrict__ b2,
    unsigned short* __restrict__ agg,   // [N][64] bf16
    float* __restrict__ cnt)
{
    __shared__ __align__(16) unsigned short sW1[64 * SW1];
    __shared__ __align__(16) unsigned char  sAH[4 * WAVE_LDS];
    __shared__ int sdst[64];

    const int t    = threadIdx.x;
    const int lane = t & 63;
    const int w    = t >> 6;

    // ---- stage W1 once per block ----
    #pragma unroll
    for (int i = 0; i < 5; i++) {
        int c = t + i * 256;
        int n = c / 20, k8 = c % 20;
        *(u16x8*)&sW1[n * SW1 + k8 * 8] = *(const u16x8*)&W1t[c * 8];
    }
    __syncthreads();                     // the only block-wide barrier

    unsigned short* myAin = (unsigned short*)(sAH + w * WAVE_LDS);
    float*          myMsg = (float*)myAin;                       // stride 84 dw
    unsigned short* myH   = (unsigned short*)(sAH + w * WAVE_LDS + 16 * SA * 2);

    if (lane < 16) {                     // zero the K-pad once
        u16x8 z = {0,0,0,0,0,0,0,0};
        *(u16x8*)&myAin[lane * SA + 144] = z;
        *(u16x8*)&myAin[lane * SA + 152] = z;
    }

    const int col = lane & 15;
    const int kq  = lane >> 4;
    const int el  = lane >> 2;
    const int q   = lane & 3;
    const int c2  = lane & 31;
    const int eh  = lane >> 5;

    // ---- per-lane constants ----
    float b1r[4], b2r[4];
    u16x8 w2f[8];
    #pragma unroll
    for (int ct = 0; ct < 4; ct++) {
        b1r[ct] = b1[ct * 16 + col];
        b2r[ct] = b2[ct * 16 + col];
        #pragma unroll
        for (int ks = 0; ks < 2; ks++)
            w2f[ks * 4 + ct] = *(const u16x8*)&W2t[(ct * 16 + col) * 64 + ks * 32 + kq * 8];
    }

    const int TW = EDGE_BLOCKS * 4;
    const int gw = blockIdx.x * 4 + w;

    // ---- prologue: gather group gw (bf16 rows: 32B/lane/endpoint) ----
    int d_cur;
    u16x8 gx[4];
    float4 fe;
    {
        int e = gw * 16 + el;
        int s = ei[e];
        d_cur = ei[N_EDGES + e];
        const u16x8* ps = (const u16x8*)(xb + (size_t)s * 64);
        const u16x8* pd = (const u16x8*)(xb + (size_t)d_cur * 64);
        gx[0] = ps[2 * q]; gx[1] = ps[2 * q + 1];
        gx[2] = pd[2 * q]; gx[3] = pd[2 * q + 1];
        fe = ((const float4*)ea)[(size_t)gw * 64 + lane];
    }

    for (int g = gw; g < N_GROUPS; g += TW) {
        const int gn = g + TW;
        const bool more = gn < N_GROUPS;
        int sn = 0, dn = 0;
        if (more) {
            int e2 = gn * 16 + el;
            sn = ei[e2];
            dn = ei[N_EDGES + e2];
        }

        // ---- commit group g to LDS ----
        unsigned short* row = myAin + el * SA;
        *(u16x8*)(row + q * 16)          = gx[0];
        *(u16x8*)(row + q * 16 + 8)      = gx[1];
        *(u16x8*)(row + 64 + q * 16)     = gx[2];
        *(u16x8*)(row + 64 + q * 16 + 8) = gx[3];
        cvt4v(&row[128 + q * 4], fe);
        if (q == 1) sdst[w * 16 + el] = d_cur;
        if (q == 2) atomicAdd(&cnt[d_cur], 1.0f);

        // ---- issue next group's gather (hidden behind GEMMs) ----
        if (more) {
            const u16x8* ps = (const u16x8*)(xb + (size_t)sn * 64);
            const u16x8* pd = (const u16x8*)(xb + (size_t)dn * 64);
            gx[0] = ps[2 * q]; gx[1] = ps[2 * q + 1];
            gx[2] = pd[2 * q]; gx[3] = pd[2 * q + 1];
            fe = ((const float4*)ea)[(size_t)gn * 64 + lane];
        }
        d_cur = dn;

        __builtin_amdgcn_wave_barrier();

        // ---- GEMM1: 16x160 @ 160x64 ----
        f32x4 acc[4] = {{0,0,0,0},{0,0,0,0},{0,0,0,0},{0,0,0,0}};
        #pragma unroll
        for (int ks = 0; ks < 5; ks++) {
            int ko = ks * 32 + kq * 8;
            bf16x8 a = lds_frag(&myAin[col * SA + ko]);
            #pragma unroll
            for (int ct = 0; ct < 4; ct++) {
                bf16x8 b = lds_frag(&sW1[(ct * 16 + col) * SW1 + ko]);
                acc[ct] = __builtin_amdgcn_mfma_f32_16x16x32_bf16(a, b, acc[ct], 0, 0, 0);
            }
        }
        #pragma unroll
        for (int ct = 0; ct < 4; ct++) {
            #pragma unroll
            for (int r = 0; r < 4; r++)
                myH[(kq * 4 + r) * SH + ct * 16 + col] =
                    f2bf(fmaxf(acc[ct][r] + b1r[ct], 0.0f));
        }
        __builtin_amdgcn_wave_barrier();

        // ---- GEMM2: 16x64 @ 64x64 (B in registers) ----
        f32x4 m[4] = {{0,0,0,0},{0,0,0,0},{0,0,0,0},{0,0,0,0}};
        #pragma unroll
        for (int ks = 0; ks < 2; ks++) {
            int ko = ks * 32 + kq * 8;
            bf16x8 a = lds_frag(&myH[col * SH + ko]);
            #pragma unroll
            for (int ct = 0; ct < 4; ct++)
                m[ct] = __builtin_amdgcn_mfma_f32_16x16x32_bf16(
                    a, __builtin_bit_cast(bf16x8, w2f[ks * 4 + ct]), m[ct], 0, 0, 0);
        }
        #pragma unroll
        for (int ct = 0; ct < 4; ct++) {
            #pragma unroll
            for (int r = 0; r < 4; r++)
                myMsg[(kq * 4 + r) * 84 + ct * 16 + col] = m[ct][r] + b2r[ct];
        }
        __builtin_amdgcn_wave_barrier();

        // ---- scatter: pk bf16 atomics — 2 edges per wave-instr, 32 ops/edge ----
        #pragma unroll 1
        for (int i = 0; i < 8; i++) {
            int   el2 = i * 2 + eh;
            int   dd  = sdst[w * 16 + el2];
            f32x2 v   = *(const f32x2*)&myMsg[el2 * 84 + c2 * 2];
            unsigned int pk = ((unsigned int)f2bf(v[1]) << 16) | f2bf(v[0]);
            atomic_pk_add_bf16(&agg[(size_t)dd * 64 + c2 * 2], pk);
        }
        __builtin_amdgcn_wave_barrier();   // scatter reads before next gather writes
    }
}

// ---- node update: [64 nodes x 128] x [128 x 64] per block, coalesced rows ----
#define NSA 136
__global__ __launch_bounds__(256, 4) void node_kernel(
    const float* __restrict__ x,
    const unsigned short* __restrict__ agg,   // bf16
    const float* __restrict__ cnt,
    const unsigned short* __restrict__ Wut,
    const float* __restrict__ bu,
    float* __restrict__ out)
{
    __shared__ __align__(16) unsigned short sA [64 * NSA];
    __shared__ __align__(16) unsigned short sWu[64 * NSA];
    const int t = threadIdx.x, lane = t & 63, w = t >> 6;
    const int n0 = blockIdx.x * 64;

    #pragma unroll
    for (int i = 0; i < 4; i++) {
        int c = t + i * 256;
        int n = c / 16, k8 = c % 16;
        *(u16x8*)&sWu[n * NSA + k8 * 8] = *(const u16x8*)&Wut[c * 8];
    }
    {
        const int nl = t >> 2, q = t & 3;
        const int n = n0 + nl;
        unsigned short* row = sA + nl * NSA;
        if (n < N_NODES) {
            const float4* px = (const float4*)(x + (size_t)n * 64);
            cvt16v(row + q * 16, px[q*4], px[q*4+1], px[q*4+2], px[q*4+3]);
            float inv = 1.0f / (cnt[n] + 1e-6f);
            const u16x8* pa = (const u16x8*)(agg + (size_t)n * 64);
            u16x8 a0 = pa[2 * q], a1 = pa[2 * q + 1];
            u16x8 r0, r1;
            #pragma unroll
            for (int j = 0; j < 8; j++) {
                r0[j] = f2bf(bf2f(a0[j]) * inv);
                r1[j] = f2bf(bf2f(a1[j]) * inv);
            }
            *(u16x8*)(row + 64 + q * 16)     = r0;
            *(u16x8*)(row + 64 + q * 16 + 8) = r1;
        } else {
            u16x8 z = {0,0,0,0,0,0,0,0};
            *(u16x8*)&row[q * 16]          = z;
            *(u16x8*)&row[q * 16 + 8]      = z;
            *(u16x8*)&row[64 + q * 16]     = z;
            *(u16x8*)&row[64 + q * 16 + 8] = z;
        }
    }
    __syncthreads();

    const int col = lane & 15, kq = lane >> 4;
    const int arow = w * 16 + col;
    f32x4 acc[4] = {{0,0,0,0},{0,0,0,0},{0,0,0,0},{0,0,0,0}};
    #pragma unroll
    for (int ks = 0; ks < 4; ks++) {
        int ko = ks * 32 + kq * 8;
        bf16x8 a = lds_frag(&sA[arow * NSA + ko]);
        #pragma unroll
        for (int ct = 0; ct < 4; ct++) {
            bf16x8 b = lds_frag(&sWu[(ct * 16 + col) * NSA + ko]);
            acc[ct] = __builtin_amdgcn_mfma_f32_16x16x32_bf16(a, b, acc[ct], 0, 0, 0);
        }
    }
    #pragma unroll
    for (int ct = 0; ct < 4; ct++) {
        float bb = bu[ct * 16 + col];
        #pragma unroll
        for (int r = 0; r < 4; r++) {
            int row = w * 16 + kq * 4 + r;
            int n = n0 + row;
            if (n < N_NODES) {
                int c2 = ct * 16 + col;
                float xa = x[(size_t)n * 64 + c2];          // exact fp32 residual
                out[(size_t)n * 64 + c2] = xa + fmaxf(acc[ct][r] + bb, 0.0f);
            }
        }
    }
}

extern "C" void kernel_launch(void* const* d_in, const int* in_sizes, int n_in,
                              void* d_out, int out_size, void* d_ws, size_t ws_size,
                              hipStream_t stream) {
    const float* x  = (const float*)d_in[0];
    const int*   ei = (const int*)  d_in[1];
    const float* ea = (const float*)d_in[2];
    const float* W1 = (const float*)d_in[3];
    const float* b1 = (const float*)d_in[4];
    const float* W2 = (const float*)d_in[5];
    const float* b2 = (const float*)d_in[6];
    const float* Wu = (const float*)d_in[7];
    const float* bu = (const float*)d_in[8];
    float* out = (float*)d_out;

    unsigned short* agg = (unsigned short*)d_ws;                // [N][64] bf16
    float* cnt = (float*)(agg + (size_t)N_NODES * HIDDEN);      // [N] f32
    unsigned short* W1t = (unsigned short*)(cnt + N_NODES);     // [64][160] bf16
    unsigned short* W2t = W1t + 64 * 160;                       // [64][64]
    unsigned short* Wut = W2t + 64 * 64;                        // [64][128]
    unsigned short* xb  = Wut + 64 * 128;                       // [N][64] bf16

    hipMemsetAsync(d_ws, 0,
                   (size_t)N_NODES * HIDDEN * sizeof(unsigned short)
                   + (size_t)N_NODES * sizeof(float), stream);

    prep_kernel<<<512, 256, 0, stream>>>(W1, W2, Wu, x, W1t, W2t, Wut, xb);
    edge_kernel<<<EDGE_BLOCKS, 256, 0, stream>>>(xb, ei, ea, W1t, W2t, b1, b2, agg, cnt);
    node_kernel<<<(N_NODES + 63) / 64, 256, 0, stream>>>(x, agg, cnt, Wut, bu, out);
}